// Round 8
// baseline (295.067 us; speedup 1.0000x reference)
//
#include <hip/hip_runtime.h>
#include <stdint.h>

// Guided_Conv R8: 256-thread blocks, 6 blocks/CU — attack block-latency-chain.
// Evidence trail: R7 removed ~100 LDS instrs/thread -> 0 gain (LDS pipe NOT
// the limit). R6 counted-vmcnt overlap -> only -8us. All pipes <40% busy,
// FETCH/WRITE pinned at 92/83 MB. Diagnosis: only 3 independent blocks/CU;
// each block is a long barrier-synced latency chain (P2/P3 run on 1-2 of 9
// waves) -> CU idles at barriers. Fix: 256-thread blocks (4 waves), LDS cut
// to 25.7 KB -> 6 resident blocks/CU (24 waves) = 2x independent chains.
// Simplifications vs R6/R7 (risk-down): plain __syncthreads everywhere; one
// overlaid LDS buffer (guidance -> dead after P2 -> depth); dense_w/dense_b/
// conv_b read from global (L2/L3-hot broadcast) instead of LDS staging.
// LDS: buf 20736 + cwf 2916 + cols 864 + sw 864 + gapm 36 + cful 324 = 25740 B.

__device__ __forceinline__ void gload16(const float* gsrc, float* ldst) {
    __builtin_amdgcn_global_load_lds(
        (__attribute__((address_space(1))) void*)gsrc,
        (__attribute__((address_space(3))) void*)ldst, 16, 0, 0);
}

__device__ __forceinline__ void do_pixel(const float* __restrict__ sd,
                                         const float* __restrict__ sw,
                                         float* __restrict__ out, int p) {
    const int row = p / 24;
    const int col = p - row * 24;
    float dc[9];
    #pragma unroll
    for (int i = 0; i < 9; ++i) dc[i] = 0.f;

    #pragma unroll
    for (int du = 0; du < 3; ++du) {
        const int r = row + du - 1;
        if (r < 0 || r > 23) continue;
        #pragma unroll
        for (int dv = 0; dv < 3; ++dv) {
            const int c = col + dv - 1;
            if (c < 0 || c > 23) continue;
            const float* sp = &sd[(r * 24 + c) * 9];   // lane stride 9: conflict-free
            const float* wv = &sw[(du * 3 + dv) * 12]; // broadcast
            #pragma unroll
            for (int i = 0; i < 9; ++i) dc[i] += sp[i] * wv[i];
        }
    }

    float* op = out + p * 9;
    #pragma unroll
    for (int o = 0; o < 9; ++o) {
        const float* wv = &sw[108 + o * 12];
        float a = 0.f;
        #pragma unroll
        for (int i = 0; i < 9; ++i) a += dc[i] * wv[i];
        op[o] = a;
    }
}

__global__ __launch_bounds__(256, 6) void fused_kernel(
    const float* __restrict__ g,
    const float* __restrict__ dep,
    const float* __restrict__ cw,
    const float* __restrict__ cb,
    const float* __restrict__ dw,
    const float* __restrict__ db,
    float* __restrict__ out)
{
    // overlay: P0-P2 = guidance patch [24][24][9]; P3-P4 = depth patch (same layout)
    __shared__ __align__(16) float buf[5184];
    __shared__ float cwf[729];                 // conv_w [du][dv][ci][o]
    __shared__ float cols[216];                // per-(col,f) sums over rows
    __shared__ __align__(16) float sw[216];    // w1[9][12] + w2t[9][12] (pads unread)
    __shared__ float gapm[9];
    __shared__ float cful[81];                 // conv out [uv][o]

    const int m = blockIdx.x;
    const int t = threadIdx.x;
    const int b0 = m >> 8, pi = (m >> 4) & 15, pj = m & 15;
    const long rowbase = ((long)(b0 * 384 + pi * 24)) * 3456 + (long)pj * 216;

    // ---- P0: conv weights -> LDS; guidance DMA -> buf; depth -> float4 regs;
    //      conv bias -> reg. All issued before one full-drain barrier; overlap
    //      across the 6 resident blocks hides the burst. ----
    for (int idx = t; idx < 729; idx += 256) cwf[idx] = cw[idx];
    for (int task = t; task < 1296; task += 256) {   // 5 tasks/thread (+1 for t<16)
        int r = task / 54, c4 = task - r * 54;
        gload16(g + rowbase + (long)r * 3456 + c4 * 4, buf + task * 4);
    }
    float4 dreg[6];
    #pragma unroll
    for (int k = 0; k < 5; ++k) {
        const int task = t + 256 * k;
        const int r = task / 54, c4 = task - r * 54;
        dreg[k] = *reinterpret_cast<const float4*>(dep + rowbase + (long)r * 3456 + c4 * 4);
    }
    if (t < 16) {
        const int task = t + 1280;
        const int r = task / 54, c4 = task - r * 54;
        dreg[5] = *reinterpret_cast<const float4*>(dep + rowbase + (long)r * 3456 + c4 * 4);
    }
    float cbv = 0.f;
    if (t < 81) cbv = cb[t % 9];
    __syncthreads();

    // ---- P1: column sums over rows (t<216; lane-contiguous reads) ----
    if (t < 216) {
        float s = 0.f;
        #pragma unroll
        for (int r = 0; r < 24; ++r) s += buf[r * 216 + t];
        cols[t] = s;
    }
    __syncthreads();

    // ---- P2: strided 3x3 conv (t<81) || GAP finish (t 96..104) ----
    if (t < 81) {
        const int o = t % 9, uv = t / 9, v = uv % 3, u = uv / 3;
        float acc = cbv;
        #pragma unroll
        for (int du = 0; du < 3; ++du)
        #pragma unroll
        for (int dv = 0; dv < 3; ++dv) {
            const float* gp2 = &buf[(u * 8 + du) * 216 + (v * 8 + dv) * 9];
            const float* wp  = &cwf[(du * 3 + dv) * 81 + o];
            #pragma unroll
            for (int ci = 0; ci < 9; ++ci) acc += gp2[ci] * wp[ci * 9];
        }
        cful[t] = acc;
    } else if (t >= 96 && t < 105) {
        const int c = t - 96;
        float s = 0.f;
        #pragma unroll
        for (int j = 0; j < 24; ++j) s += cols[j * 9 + c];   // stride 9: no conflicts
        gapm[c] = s * (1.0f / 576.0f);
    }
    __syncthreads();   // last guidance readers done -> buf reusable

    // ---- P3: depth regs -> buf (b128, lane-contiguous) || dense + W2 clip
    //      (t<9; dense_w/dense_b from global, L2-hot) || W1 clip (t 64..72) ----
    {
        float4* b4 = reinterpret_cast<float4*>(buf);
        #pragma unroll
        for (int k = 0; k < 5; ++k) b4[t + 256 * k] = dreg[k];
        if (t < 16) b4[t + 1280] = dreg[5];
    }
    if (t < 9) {
        float gv[9];
        #pragma unroll
        for (int k = 0; k < 9; ++k) gv[k] = gapm[k];
        float d[9];
        float ss = 0.f;
        #pragma unroll
        for (int i = 0; i < 9; ++i) {
            float a = db[i * 9 + t];
            #pragma unroll
            for (int k = 0; k < 9; ++k) a += gv[k] * dw[k * 81 + i * 9 + t];
            d[i] = a; ss += a * a;
        }
        const float scale = (ss > 1.0f) ? (1.0f / sqrtf(ss)) : 1.0f;
        #pragma unroll
        for (int i = 0; i < 9; ++i) sw[108 + t * 12 + i] = d[i] * scale;
    } else if (t >= 64 && t < 73) {
        const int f = t - 64;
        float ss = 0.f;
        #pragma unroll
        for (int k = 0; k < 9; ++k) { const float c = cful[k * 9 + f]; ss += c * c; }
        const float scale = (ss > 1.0f) ? (1.0f / sqrtf(ss)) : 1.0f;
        #pragma unroll
        for (int k = 0; k < 9; ++k) sw[k * 12 + f] = cful[k * 9 + f] * scale;
    }
    __syncthreads();   // depth + generated weights visible

    // ---- P4: 2-3 pixels/thread (pixel ids t, t+256, t+512 keep lane-stride 9) ----
    {
        float* ob = out + (long)m * 5184;
        do_pixel(buf, sw, ob, t);
        do_pixel(buf, sw, ob, t + 256);
        if (t < 64) do_pixel(buf, sw, ob, t + 512);
    }
}

extern "C" void kernel_launch(void* const* d_in, const int* in_sizes, int n_in,
                              void* d_out, int out_size, void* d_ws, size_t ws_size,
                              hipStream_t stream) {
    const float* g  = (const float*)d_in[0];
    const float* dp = (const float*)d_in[1];
    const float* cw = (const float*)d_in[2];
    const float* cb = (const float*)d_in[3];
    const float* dw = (const float*)d_in[4];
    const float* db = (const float*)d_in[5];
    float* out = (float*)d_out;
    (void)d_ws; (void)ws_size;

    fused_kernel<<<dim3(4096), dim3(256), 0, stream>>>(g, dp, cw, cb, dw, db, out);
}